// Round 1
// baseline (313.295 us; speedup 1.0000x reference)
//
#include <hip/hip_runtime.h>
#include <cstdint>

// Chamfer distance, B=8, N=M=4096, D=128, f32 in, scalar f32 out.
// Strategy: bf16 MFMA for the -2<x,y> GEMM (fp32 norms), fused min-reduction
// epilogue with uint-bits atomicMin (distances >= 0), never materialize D.
// Workspace: xb(8MiB) yb(8MiB) x2(128KiB) y2(128KiB) rowmin(128KiB)
//            colmin(128KiB) partial(512B)  => ~16.6 MiB total.

#define B_   8
#define N_   4096
#define M_   4096
#define D_   128
#define LDP  136   // padded LDS row stride in bf16 elems (272B = 17*16B: aligned, rotates banks by 4/row)

typedef __bf16 bf16x8 __attribute__((ext_vector_type(8)));
typedef float  f32x4  __attribute__((ext_vector_type(4)));

static __device__ __forceinline__ unsigned short f2bf(float f) {
  unsigned u = __float_as_uint(f);
  u += 0x7FFFu + ((u >> 16) & 1u);   // round-to-nearest-even
  return (unsigned short)(u >> 16);
}

// Pass 1: one wave per row (x rows then y rows). fp32 sum-of-squares,
// f32->bf16 convert, and init of the min arrays to +inf.
__global__ __launch_bounds__(256) void pass1_prep(
    const float* __restrict__ x, const float* __restrict__ y,
    unsigned short* __restrict__ xb, unsigned short* __restrict__ yb,
    float* __restrict__ x2, float* __restrict__ y2,
    unsigned* __restrict__ rowmin, unsigned* __restrict__ colmin)
{
  const int ROWS = B_ * N_;
  int gw   = (blockIdx.x * 256 + threadIdx.x) >> 6;
  int lane = threadIdx.x & 63;
  const float* src; unsigned short* dst; float* nrm; unsigned* mn; int row;
  if (gw < ROWS) { src = x; dst = xb; nrm = x2; mn = rowmin; row = gw; }
  else           { src = y; dst = yb; nrm = y2; mn = colmin; row = gw - ROWS; }
  size_t base = (size_t)row * D_ + lane * 2;
  float2 v = *(const float2*)(src + base);
  unsigned packed = (unsigned)f2bf(v.x) | ((unsigned)f2bf(v.y) << 16);
  *(unsigned*)(dst + base) = packed;
  float s = v.x * v.x + v.y * v.y;
  #pragma unroll
  for (int m = 1; m < 64; m <<= 1) s += __shfl_xor(s, m, 64);
  if (lane == 0) { nrm[row] = s; mn[row] = 0x7F800000u; }
}

// Pass 2: 128x128 distance tile per block (256 thr = 4 waves).
// Wave w computes rows w*32..w*32+31 x all 128 cols via 2x8 grid of
// 16x16x32 bf16 MFMAs, K=128 in 4 steps. Fragment layouts (HW-verified):
//   A/B operand: lane holds elems [row=lane&15][k=(lane>>4)*8 + 0..7]
//   C/D:         lane reg r holds [row=(lane>>4)*4+r][col=lane&15]
__global__ __launch_bounds__(256) void pass2_tile(
    const unsigned short* __restrict__ xb, const unsigned short* __restrict__ yb,
    const float* __restrict__ x2, const float* __restrict__ y2,
    unsigned* __restrict__ rowmin, unsigned* __restrict__ colmin)
{
  __shared__ alignas(16) unsigned short xs[128 * LDP];
  __shared__ alignas(16) unsigned short ys[128 * LDP];
  __shared__ float x2s[128];
  __shared__ float y2s[128];
  __shared__ unsigned cminS[128];

  const int b   = blockIdx.z;
  const int n0  = blockIdx.x * 128;
  const int m0  = blockIdx.y * 128;
  const int tid = threadIdx.x;

  const size_t xbase = ((size_t)b * N_ + n0) * D_;
  const size_t ybase = ((size_t)b * M_ + m0) * D_;

  // Stage both tiles: 128 rows x 128 bf16 = 16 x 16B chunks per row.
  #pragma unroll
  for (int i = 0; i < 8; ++i) {
    int idx = i * 256 + tid;
    int r = idx >> 4;
    int c = (idx & 15) << 3;
    *(uint4*)(xs + r * LDP + c) = *(const uint4*)(xb + xbase + r * D_ + c);
    *(uint4*)(ys + r * LDP + c) = *(const uint4*)(yb + ybase + r * D_ + c);
  }
  if (tid < 128) { x2s[tid] = x2[b * N_ + n0 + tid]; cminS[tid] = 0x7F800000u; }
  else           { y2s[tid - 128] = y2[b * M_ + m0 + tid - 128]; }
  __syncthreads();

  const int wave = tid >> 6;
  const int lane = tid & 63;
  const int quad = lane >> 4;
  const int l15  = lane & 15;
  const int rowbase = wave * 32;

  f32x4 acc[2][8];
  #pragma unroll
  for (int rt = 0; rt < 2; ++rt)
    #pragma unroll
    for (int ct = 0; ct < 8; ++ct)
      acc[rt][ct] = (f32x4)(0.0f);

  #pragma unroll
  for (int kb = 0; kb < 4; ++kb) {
    const int koff = kb * 32 + quad * 8;
    bf16x8 a0 = *(const bf16x8*)(xs + (rowbase      + l15) * LDP + koff);
    bf16x8 a1 = *(const bf16x8*)(xs + (rowbase + 16 + l15) * LDP + koff);
    #pragma unroll
    for (int ct = 0; ct < 8; ++ct) {
      bf16x8 bfr = *(const bf16x8*)(ys + (ct * 16 + l15) * LDP + koff);
      acc[0][ct] = __builtin_amdgcn_mfma_f32_16x16x32_bf16(a0, bfr, acc[0][ct], 0, 0, 0);
      acc[1][ct] = __builtin_amdgcn_mfma_f32_16x16x32_bf16(a1, bfr, acc[1][ct], 0, 0, 0);
    }
  }

  const float FINF = __uint_as_float(0x7F800000u);

  float xv[2][4];
  #pragma unroll
  for (int rt = 0; rt < 2; ++rt)
    #pragma unroll
    for (int r = 0; r < 4; ++r)
      xv[rt][r] = x2s[rowbase + rt * 16 + quad * 4 + r];

  float rmin[2][4];
  #pragma unroll
  for (int rt = 0; rt < 2; ++rt)
    #pragma unroll
    for (int r = 0; r < 4; ++r) rmin[rt][r] = FINF;

  float cmin[8];
  #pragma unroll
  for (int ct = 0; ct < 8; ++ct) {
    float yv = y2s[ct * 16 + l15];
    float cm = FINF;
    #pragma unroll
    for (int rt = 0; rt < 2; ++rt) {
      #pragma unroll
      for (int r = 0; r < 4; ++r) {
        float d2 = xv[rt][r] + yv - 2.0f * acc[rt][ct][r];
        float d  = sqrtf(fmaxf(d2, 0.0f));
        rmin[rt][r] = fminf(rmin[rt][r], d);
        cm = fminf(cm, d);
      }
    }
    cmin[ct] = cm;
  }

  // Row mins (min over this tile's 128 cols): reduce across the 16 lanes of
  // each quad (cols), then one atomic per row.
  #pragma unroll
  for (int rt = 0; rt < 2; ++rt) {
    #pragma unroll
    for (int r = 0; r < 4; ++r) {
      float v = rmin[rt][r];
      v = fminf(v, __shfl_xor(v, 1, 64));
      v = fminf(v, __shfl_xor(v, 2, 64));
      v = fminf(v, __shfl_xor(v, 4, 64));
      v = fminf(v, __shfl_xor(v, 8, 64));
      if (l15 == 0) {
        int row = rowbase + rt * 16 + quad * 4 + r;
        atomicMin(rowmin + (size_t)b * N_ + n0 + row, __float_as_uint(v));
      }
    }
  }

  // Col mins: reduce across quads (rows) in-wave, combine the 4 waves in LDS,
  // then 128 global atomics per block.
  #pragma unroll
  for (int ct = 0; ct < 8; ++ct) {
    float v = cmin[ct];
    v = fminf(v, __shfl_xor(v, 16, 64));
    v = fminf(v, __shfl_xor(v, 32, 64));
    if (lane < 16) atomicMin(&cminS[ct * 16 + lane], __float_as_uint(v));
  }
  __syncthreads();
  if (tid < 128) atomicMin(colmin + (size_t)b * M_ + m0 + tid, cminS[tid]);
}

// Pass 3: partial sums of both min arrays (64 blocks).
__global__ __launch_bounds__(256) void pass3_partial(
    const unsigned* __restrict__ rowmin, const unsigned* __restrict__ colmin,
    float* __restrict__ partial)
{
  float s1 = 0.0f, s2 = 0.0f;
  for (int i = blockIdx.x * 256 + threadIdx.x; i < B_ * N_; i += 64 * 256) {
    s1 += __uint_as_float(rowmin[i]);
    s2 += __uint_as_float(colmin[i]);
  }
  #pragma unroll
  for (int m = 1; m < 64; m <<= 1) { s1 += __shfl_xor(s1, m, 64); s2 += __shfl_xor(s2, m, 64); }
  __shared__ float r1[4], r2[4];
  int wave = threadIdx.x >> 6, lane = threadIdx.x & 63;
  if (lane == 0) { r1[wave] = s1; r2[wave] = s2; }
  __syncthreads();
  if (threadIdx.x == 0) {
    partial[blockIdx.x]      = r1[0] + r1[1] + r1[2] + r1[3];
    partial[64 + blockIdx.x] = r2[0] + r2[1] + r2[2] + r2[3];
  }
}

// Pass 4: final 64->1 reduce, write scalar loss.
__global__ void pass4_final(const float* __restrict__ partial, float* __restrict__ out)
{
  int lane = threadIdx.x;
  float s = partial[lane] + partial[64 + lane];
  #pragma unroll
  for (int m = 1; m < 64; m <<= 1) s += __shfl_xor(s, m, 64);
  if (lane == 0) out[0] = s / (float)(B_ * N_);
}

extern "C" void kernel_launch(void* const* d_in, const int* in_sizes, int n_in,
                              void* d_out, int out_size, void* d_ws, size_t ws_size,
                              hipStream_t stream)
{
  const float* x = (const float*)d_in[0];
  const float* y = (const float*)d_in[1];
  char* ws = (char*)d_ws;

  unsigned short* xb = (unsigned short*)(ws);
  unsigned short* yb = (unsigned short*)(ws + (8u << 20));
  float*    x2     = (float*)   (ws + (16u << 20));
  float*    y2     = (float*)   (ws + (16u << 20) + (1u << 17));
  unsigned* rowmin = (unsigned*)(ws + (16u << 20) + (2u << 17));
  unsigned* colmin = (unsigned*)(ws + (16u << 20) + (3u << 17));
  float*    partial= (float*)   (ws + (16u << 20) + (4u << 17));
  float* outf = (float*)d_out;

  // 65536 rows total, one wave per row, 4 waves per block.
  pass1_prep<<<(2 * B_ * N_) / 4, 256, 0, stream>>>(x, y, xb, yb, x2, y2, rowmin, colmin);

  dim3 g2(N_ / 128, M_ / 128, B_);
  pass2_tile<<<g2, 256, 0, stream>>>(xb, yb, x2, y2, rowmin, colmin);

  pass3_partial<<<64, 256, 0, stream>>>(rowmin, colmin, partial);
  pass4_final<<<1, 64, 0, stream>>>(partial, outf);
}

// Round 2
// 181.883 us; speedup vs baseline: 1.7225x; 1.7225x over previous
//
#include <hip/hip_runtime.h>
#include <cstdint>

// Chamfer distance, B=8, N=M=4096, D=128, f32 in, scalar f32 out.
// R2: M-loop-per-block structure. A (= -2x, bf16) held in registers across
// 8 y-tile iterations; accumulator initialized to x2_i so epilogue is
// 1 add + 2 min per element; all mins done on d^2, sqrt deferred to pass3.
// Workspace: xb(8MiB) yb(8MiB) x2(128KiB) y2(128KiB) rowmin(128KiB)
//            colmin(128KiB) partial(512B).

#define B_   8
#define N_   4096
#define M_   4096
#define D_   128
#define LDP  136   // padded LDS row stride in bf16 elems (272B: 16B-aligned, rotates banks 4/row)
#define TPB  8     // y-tiles per block
#define CHUNKS (M_ / 128 / TPB)   // 4

typedef __bf16 bf16x8 __attribute__((ext_vector_type(8)));
typedef float  f32x4  __attribute__((ext_vector_type(4)));

static __device__ __forceinline__ unsigned short f2bf(float f) {
  unsigned u = __float_as_uint(f);
  u += 0x7FFFu + ((u >> 16) & 1u);   // round-to-nearest-even
  return (unsigned short)(u >> 16);
}

// Pass 1: one wave per row. xb = bf16(-2x) (exact scale), yb = bf16(y),
// fp32 norms from the original f32 data, min arrays init to +inf bits.
__global__ __launch_bounds__(256) void pass1_prep(
    const float* __restrict__ x, const float* __restrict__ y,
    unsigned short* __restrict__ xb, unsigned short* __restrict__ yb,
    float* __restrict__ x2, float* __restrict__ y2,
    unsigned* __restrict__ rowmin, unsigned* __restrict__ colmin)
{
  const int ROWS = B_ * N_;
  int gw   = (blockIdx.x * 256 + threadIdx.x) >> 6;
  int lane = threadIdx.x & 63;
  bool isx = gw < ROWS;
  const float* src; unsigned short* dst; float* nrm; unsigned* mn; int row;
  if (isx) { src = x; dst = xb; nrm = x2; mn = rowmin; row = gw; }
  else     { src = y; dst = yb; nrm = y2; mn = colmin; row = gw - ROWS; }
  size_t base = (size_t)row * D_ + lane * 2;
  float2 v = *(const float2*)(src + base);
  float sx = isx ? -2.0f : 1.0f;
  unsigned packed = (unsigned)f2bf(sx * v.x) | ((unsigned)f2bf(sx * v.y) << 16);
  *(unsigned*)(dst + base) = packed;
  float s = v.x * v.x + v.y * v.y;
  #pragma unroll
  for (int m = 1; m < 64; m <<= 1) s += __shfl_xor(s, m, 64);
  if (lane == 0) { nrm[row] = s; mn[row] = 0x7F800000u; }
}

// Pass 2: block = 128 x-rows (4 waves x 32 rows), loops over TPB y-tiles of
// 128 cols. 16x16x32 bf16 MFMA. Fragment layouts (HW-verified):
//   A/B operand: lane holds elems [row=lane&15][k=(lane>>4)*8 + 0..7]
//   C/D:         lane reg r holds [row=(lane>>4)*4+r][col=lane&15]
// acc init = x2_row, so acc_final = x2_i - 2<x_i,y_j>; add y2_j -> d^2.
__global__ __launch_bounds__(256, 4) void pass2_tile(
    const unsigned short* __restrict__ xb, const unsigned short* __restrict__ yb,
    const float* __restrict__ x2, const float* __restrict__ y2,
    unsigned* __restrict__ rowmin, unsigned* __restrict__ colmin)
{
  __shared__ alignas(16) unsigned short ys[128 * LDP];
  __shared__ float y2s[128];
  __shared__ unsigned cminS[128];

  const int b   = blockIdx.z;
  const int n0  = blockIdx.x * 128;
  const int mc0 = blockIdx.y * (TPB * 128);
  const int tid  = threadIdx.x;
  const int wave = tid >> 6;
  const int lane = tid & 63;
  const int quad = lane >> 4;
  const int l15  = lane & 15;
  const int rowbase = wave * 32;

  // --- Stage x-tile into the (shared) buffer once, pull A-frags to regs ---
  const size_t xbase = ((size_t)b * N_ + n0) * D_;
  #pragma unroll
  for (int i = 0; i < 8; ++i) {
    int idx = i * 256 + tid;
    int r = idx >> 4;
    int c = (idx & 15) << 3;
    *(uint4*)(ys + r * LDP + c) = *(const uint4*)(xb + xbase + r * D_ + c);
  }
  if (tid < 128) cminS[tid] = 0x7F800000u;
  __syncthreads();

  bf16x8 afrag[4][2];
  #pragma unroll
  for (int kb = 0; kb < 4; ++kb) {
    const int koff = kb * 32 + quad * 8;
    afrag[kb][0] = *(const bf16x8*)(ys + (rowbase      + l15) * LDP + koff);
    afrag[kb][1] = *(const bf16x8*)(ys + (rowbase + 16 + l15) * LDP + koff);
  }
  float xv[2][4];
  #pragma unroll
  for (int rt = 0; rt < 2; ++rt)
    #pragma unroll
    for (int r = 0; r < 4; ++r)
      xv[rt][r] = x2[(size_t)b * N_ + n0 + rowbase + rt * 16 + quad * 4 + r];

  const float FINF = __uint_as_float(0x7F800000u);
  float rmin2[2][4];
  #pragma unroll
  for (int rt = 0; rt < 2; ++rt)
    #pragma unroll
    for (int r = 0; r < 4; ++r) rmin2[rt][r] = FINF;

  __syncthreads();  // all waves finished reading x-tile; buffer now free for y

  #pragma unroll 1
  for (int t = 0; t < TPB; ++t) {
    const int m0 = mc0 + t * 128;
    const size_t ybase = ((size_t)b * M_ + m0) * D_;
    #pragma unroll
    for (int i = 0; i < 8; ++i) {
      int idx = i * 256 + tid;
      int r = idx >> 4;
      int c = (idx & 15) << 3;
      *(uint4*)(ys + r * LDP + c) = *(const uint4*)(yb + ybase + r * D_ + c);
    }
    if (tid < 128) y2s[tid] = y2[(size_t)b * M_ + m0 + tid];
    __syncthreads();

    f32x4 acc[2][8];
    #pragma unroll
    for (int rt = 0; rt < 2; ++rt)
      #pragma unroll
      for (int ct = 0; ct < 8; ++ct) {
        acc[rt][ct][0] = xv[rt][0];
        acc[rt][ct][1] = xv[rt][1];
        acc[rt][ct][2] = xv[rt][2];
        acc[rt][ct][3] = xv[rt][3];
      }

    #pragma unroll
    for (int kb = 0; kb < 4; ++kb) {
      const int koff = kb * 32 + quad * 8;
      #pragma unroll
      for (int ct = 0; ct < 8; ++ct) {
        bf16x8 bfr = *(const bf16x8*)(ys + (ct * 16 + l15) * LDP + koff);
        acc[0][ct] = __builtin_amdgcn_mfma_f32_16x16x32_bf16(afrag[kb][0], bfr, acc[0][ct], 0, 0, 0);
        acc[1][ct] = __builtin_amdgcn_mfma_f32_16x16x32_bf16(afrag[kb][1], bfr, acc[1][ct], 0, 0, 0);
      }
    }

    // Epilogue on d^2: s = acc + y2_j; track row-min and col-min.
    #pragma unroll
    for (int ct = 0; ct < 8; ++ct) {
      float yv = y2s[ct * 16 + l15];
      float cm = FINF;
      #pragma unroll
      for (int rt = 0; rt < 2; ++rt) {
        #pragma unroll
        for (int r = 0; r < 4; ++r) {
          float s = acc[rt][ct][r] + yv;
          rmin2[rt][r] = fminf(rmin2[rt][r], s);
          cm = fminf(cm, s);
        }
      }
      // col-min: reduce across quads (rows) in-wave, then LDS combine
      cm = fminf(cm, __shfl_xor(cm, 16, 64));
      cm = fminf(cm, __shfl_xor(cm, 32, 64));
      if (lane < 16) atomicMin(&cminS[ct * 16 + lane], __float_as_uint(cm));
    }
    __syncthreads();

    if (tid < 128) {
      unsigned v = cminS[tid];
      atomicMin(colmin + (size_t)b * M_ + m0 + tid, v);
      cminS[tid] = 0x7F800000u;   // re-init for next tile (safe: fenced by next barrier)
    }
  }

  // Row mins: reduce across the 16 lanes of each quad (cols), one atomic/row.
  #pragma unroll
  for (int rt = 0; rt < 2; ++rt) {
    #pragma unroll
    for (int r = 0; r < 4; ++r) {
      float v = rmin2[rt][r];
      v = fminf(v, __shfl_xor(v, 1, 64));
      v = fminf(v, __shfl_xor(v, 2, 64));
      v = fminf(v, __shfl_xor(v, 4, 64));
      v = fminf(v, __shfl_xor(v, 8, 64));
      if (l15 == 0) {
        int row = rowbase + rt * 16 + quad * 4 + r;
        atomicMin(rowmin + (size_t)b * N_ + n0 + row, __float_as_uint(v));
      }
    }
  }
}

// Pass 3: partial sums of sqrt(max(min_d2,0)) (64 blocks).
__global__ __launch_bounds__(256) void pass3_partial(
    const unsigned* __restrict__ rowmin, const unsigned* __restrict__ colmin,
    float* __restrict__ partial)
{
  float s1 = 0.0f, s2 = 0.0f;
  for (int i = blockIdx.x * 256 + threadIdx.x; i < B_ * N_; i += 64 * 256) {
    s1 += sqrtf(fmaxf(__uint_as_float(rowmin[i]), 0.0f));
    s2 += sqrtf(fmaxf(__uint_as_float(colmin[i]), 0.0f));
  }
  #pragma unroll
  for (int m = 1; m < 64; m <<= 1) { s1 += __shfl_xor(s1, m, 64); s2 += __shfl_xor(s2, m, 64); }
  __shared__ float r1[4], r2[4];
  int wave = threadIdx.x >> 6, lane = threadIdx.x & 63;
  if (lane == 0) { r1[wave] = s1; r2[wave] = s2; }
  __syncthreads();
  if (threadIdx.x == 0) {
    partial[blockIdx.x]      = r1[0] + r1[1] + r1[2] + r1[3];
    partial[64 + blockIdx.x] = r2[0] + r2[1] + r2[2] + r2[3];
  }
}

// Pass 4: final 64->1 reduce, write scalar loss.
__global__ void pass4_final(const float* __restrict__ partial, float* __restrict__ out)
{
  int lane = threadIdx.x;
  float s = partial[lane] + partial[64 + lane];
  #pragma unroll
  for (int m = 1; m < 64; m <<= 1) s += __shfl_xor(s, m, 64);
  if (lane == 0) out[0] = s / (float)(B_ * N_);
}

extern "C" void kernel_launch(void* const* d_in, const int* in_sizes, int n_in,
                              void* d_out, int out_size, void* d_ws, size_t ws_size,
                              hipStream_t stream)
{
  const float* x = (const float*)d_in[0];
  const float* y = (const float*)d_in[1];
  char* ws = (char*)d_ws;

  unsigned short* xb = (unsigned short*)(ws);
  unsigned short* yb = (unsigned short*)(ws + (8u << 20));
  float*    x2     = (float*)   (ws + (16u << 20));
  float*    y2     = (float*)   (ws + (16u << 20) + (1u << 17));
  unsigned* rowmin = (unsigned*)(ws + (16u << 20) + (2u << 17));
  unsigned* colmin = (unsigned*)(ws + (16u << 20) + (3u << 17));
  float*    partial= (float*)   (ws + (16u << 20) + (4u << 17));
  float* outf = (float*)d_out;

  pass1_prep<<<(2 * B_ * N_) / 4, 256, 0, stream>>>(x, y, xb, yb, x2, y2, rowmin, colmin);

  dim3 g2(N_ / 128, CHUNKS, B_);
  pass2_tile<<<g2, 256, 0, stream>>>(xb, yb, x2, y2, rowmin, colmin);

  pass3_partial<<<64, 256, 0, stream>>>(rowmin, colmin, partial);
  pass4_final<<<1, 64, 0, stream>>>(partial, outf);
}

// Round 3
// 181.457 us; speedup vs baseline: 1.7266x; 1.0023x over previous
//
#include <hip/hip_runtime.h>
#include <cstdint>

// Chamfer distance, B=8, N=M=4096, D=128, f32 in, scalar f32 out.
// R3: XCD-locality swizzle. All 1024 pass2 blocks are co-resident (4/CU);
// remap linear block id so XCD k (blockIdx%8 round-robin) handles batch b=k
// exclusively -> per-XCD working set (xb+yb slice) = 2 MB, fits 4 MB L2.
// Kills the 246 MB fabric re-read stream seen in R2.
// Workspace: xb(8MiB) yb(8MiB) x2(128KiB) y2(128KiB) rowmin(128KiB)
//            colmin(128KiB) partial(512B).

#define B_   8
#define N_   4096
#define M_   4096
#define D_   128
#define LDP  136   // padded LDS row stride in bf16 elems (272B: 16B-aligned, rotates banks 4/row)
#define TPB  8     // y-tiles per block
#define CHUNKS (M_ / 128 / TPB)   // 4

typedef __bf16 bf16x8 __attribute__((ext_vector_type(8)));
typedef float  f32x4  __attribute__((ext_vector_type(4)));

static __device__ __forceinline__ unsigned short f2bf(float f) {
  unsigned u = __float_as_uint(f);
  u += 0x7FFFu + ((u >> 16) & 1u);   // round-to-nearest-even
  return (unsigned short)(u >> 16);
}

// Pass 1: one wave per row. xb = bf16(-2x) (exact scale), yb = bf16(y),
// fp32 norms from the original f32 data, min arrays init to +inf bits.
__global__ __launch_bounds__(256) void pass1_prep(
    const float* __restrict__ x, const float* __restrict__ y,
    unsigned short* __restrict__ xb, unsigned short* __restrict__ yb,
    float* __restrict__ x2, float* __restrict__ y2,
    unsigned* __restrict__ rowmin, unsigned* __restrict__ colmin)
{
  const int ROWS = B_ * N_;
  int gw   = (blockIdx.x * 256 + threadIdx.x) >> 6;
  int lane = threadIdx.x & 63;
  bool isx = gw < ROWS;
  const float* src; unsigned short* dst; float* nrm; unsigned* mn; int row;
  if (isx) { src = x; dst = xb; nrm = x2; mn = rowmin; row = gw; }
  else     { src = y; dst = yb; nrm = y2; mn = colmin; row = gw - ROWS; }
  size_t base = (size_t)row * D_ + lane * 2;
  float2 v = *(const float2*)(src + base);
  float sx = isx ? -2.0f : 1.0f;
  unsigned packed = (unsigned)f2bf(sx * v.x) | ((unsigned)f2bf(sx * v.y) << 16);
  *(unsigned*)(dst + base) = packed;
  float s = v.x * v.x + v.y * v.y;
  #pragma unroll
  for (int m = 1; m < 64; m <<= 1) s += __shfl_xor(s, m, 64);
  if (lane == 0) { nrm[row] = s; mn[row] = 0x7F800000u; }
}

// Pass 2: block = 128 x-rows (4 waves x 32 rows), loops over TPB y-tiles of
// 128 cols. 16x16x32 bf16 MFMA. Fragment layouts (HW-verified):
//   A/B operand: lane holds elems [row=lane&15][k=(lane>>4)*8 + 0..7]
//   C/D:         lane reg r holds [row=(lane>>4)*4+r][col=lane&15]
// acc init = x2_row, so acc_final = x2_i - 2<x_i,y_j>; add y2_j -> d^2.
// 1-D grid of 1024; b = blockIdx%8 puts each batch on one XCD (round-robin).
__global__ __launch_bounds__(256, 4) void pass2_tile(
    const unsigned short* __restrict__ xb, const unsigned short* __restrict__ yb,
    const float* __restrict__ x2, const float* __restrict__ y2,
    unsigned* __restrict__ rowmin, unsigned* __restrict__ colmin)
{
  __shared__ alignas(16) unsigned short ys[128 * LDP];
  __shared__ float y2s[128];
  __shared__ unsigned cminS[128];

  const int L     = blockIdx.x;        // 0..1023
  const int b     = L & 7;             // XCD id == batch id (round-robin dispatch)
  const int j     = L >> 3;            // 0..127 within the XCD
  const int n0    = (j & 31) * 128;    // x-tile
  const int mc0   = (j >> 5) * (TPB * 128);  // y-chunk
  const int tid  = threadIdx.x;
  const int wave = tid >> 6;
  const int lane = tid & 63;
  const int quad = lane >> 4;
  const int l15  = lane & 15;
  const int rowbase = wave * 32;

  // --- Stage x-tile into the (shared) buffer once, pull A-frags to regs ---
  const size_t xbase = ((size_t)b * N_ + n0) * D_;
  #pragma unroll
  for (int i = 0; i < 8; ++i) {
    int idx = i * 256 + tid;
    int r = idx >> 4;
    int c = (idx & 15) << 3;
    *(uint4*)(ys + r * LDP + c) = *(const uint4*)(xb + xbase + r * D_ + c);
  }
  if (tid < 128) cminS[tid] = 0x7F800000u;
  __syncthreads();

  bf16x8 afrag[4][2];
  #pragma unroll
  for (int kb = 0; kb < 4; ++kb) {
    const int koff = kb * 32 + quad * 8;
    afrag[kb][0] = *(const bf16x8*)(ys + (rowbase      + l15) * LDP + koff);
    afrag[kb][1] = *(const bf16x8*)(ys + (rowbase + 16 + l15) * LDP + koff);
  }
  float xv[2][4];
  #pragma unroll
  for (int rt = 0; rt < 2; ++rt)
    #pragma unroll
    for (int r = 0; r < 4; ++r)
      xv[rt][r] = x2[(size_t)b * N_ + n0 + rowbase + rt * 16 + quad * 4 + r];

  const float FINF = __uint_as_float(0x7F800000u);
  float rmin2[2][4];
  #pragma unroll
  for (int rt = 0; rt < 2; ++rt)
    #pragma unroll
    for (int r = 0; r < 4; ++r) rmin2[rt][r] = FINF;

  __syncthreads();  // all waves finished reading x-tile; buffer now free for y

  #pragma unroll 1
  for (int t = 0; t < TPB; ++t) {
    const int m0 = mc0 + t * 128;
    const size_t ybase = ((size_t)b * M_ + m0) * D_;
    #pragma unroll
    for (int i = 0; i < 8; ++i) {
      int idx = i * 256 + tid;
      int r = idx >> 4;
      int c = (idx & 15) << 3;
      *(uint4*)(ys + r * LDP + c) = *(const uint4*)(yb + ybase + r * D_ + c);
    }
    if (tid < 128) y2s[tid] = y2[(size_t)b * M_ + m0 + tid];
    __syncthreads();

    f32x4 acc[2][8];
    #pragma unroll
    for (int rt = 0; rt < 2; ++rt)
      #pragma unroll
      for (int ct = 0; ct < 8; ++ct) {
        acc[rt][ct][0] = xv[rt][0];
        acc[rt][ct][1] = xv[rt][1];
        acc[rt][ct][2] = xv[rt][2];
        acc[rt][ct][3] = xv[rt][3];
      }

    #pragma unroll
    for (int kb = 0; kb < 4; ++kb) {
      const int koff = kb * 32 + quad * 8;
      #pragma unroll
      for (int ct = 0; ct < 8; ++ct) {
        bf16x8 bfr = *(const bf16x8*)(ys + (ct * 16 + l15) * LDP + koff);
        acc[0][ct] = __builtin_amdgcn_mfma_f32_16x16x32_bf16(afrag[kb][0], bfr, acc[0][ct], 0, 0, 0);
        acc[1][ct] = __builtin_amdgcn_mfma_f32_16x16x32_bf16(afrag[kb][1], bfr, acc[1][ct], 0, 0, 0);
      }
    }

    // Epilogue on d^2: s = acc + y2_j; track row-min and col-min.
    #pragma unroll
    for (int ct = 0; ct < 8; ++ct) {
      float yv = y2s[ct * 16 + l15];
      float cm = FINF;
      #pragma unroll
      for (int rt = 0; rt < 2; ++rt) {
        #pragma unroll
        for (int r = 0; r < 4; ++r) {
          float s = acc[rt][ct][r] + yv;
          rmin2[rt][r] = fminf(rmin2[rt][r], s);
          cm = fminf(cm, s);
        }
      }
      // col-min: reduce across quads (rows) in-wave, then LDS combine
      cm = fminf(cm, __shfl_xor(cm, 16, 64));
      cm = fminf(cm, __shfl_xor(cm, 32, 64));
      if (lane < 16) atomicMin(&cminS[ct * 16 + lane], __float_as_uint(cm));
    }
    __syncthreads();

    if (tid < 128) {
      unsigned v = cminS[tid];
      atomicMin(colmin + (size_t)b * M_ + m0 + tid, v);
      cminS[tid] = 0x7F800000u;   // re-init for next tile (safe: fenced by next barrier)
    }
  }

  // Row mins: reduce across the 16 lanes of each quad (cols), one atomic/row.
  #pragma unroll
  for (int rt = 0; rt < 2; ++rt) {
    #pragma unroll
    for (int r = 0; r < 4; ++r) {
      float v = rmin2[rt][r];
      v = fminf(v, __shfl_xor(v, 1, 64));
      v = fminf(v, __shfl_xor(v, 2, 64));
      v = fminf(v, __shfl_xor(v, 4, 64));
      v = fminf(v, __shfl_xor(v, 8, 64));
      if (l15 == 0) {
        int row = rowbase + rt * 16 + quad * 4 + r;
        atomicMin(rowmin + (size_t)b * N_ + n0 + row, __float_as_uint(v));
      }
    }
  }
}

// Pass 3: partial sums of sqrt(max(min_d2,0)) (64 blocks).
__global__ __launch_bounds__(256) void pass3_partial(
    const unsigned* __restrict__ rowmin, const unsigned* __restrict__ colmin,
    float* __restrict__ partial)
{
  float s1 = 0.0f, s2 = 0.0f;
  for (int i = blockIdx.x * 256 + threadIdx.x; i < B_ * N_; i += 64 * 256) {
    s1 += sqrtf(fmaxf(__uint_as_float(rowmin[i]), 0.0f));
    s2 += sqrtf(fmaxf(__uint_as_float(colmin[i]), 0.0f));
  }
  #pragma unroll
  for (int m = 1; m < 64; m <<= 1) { s1 += __shfl_xor(s1, m, 64); s2 += __shfl_xor(s2, m, 64); }
  __shared__ float r1[4], r2[4];
  int wave = threadIdx.x >> 6, lane = threadIdx.x & 63;
  if (lane == 0) { r1[wave] = s1; r2[wave] = s2; }
  __syncthreads();
  if (threadIdx.x == 0) {
    partial[blockIdx.x]      = r1[0] + r1[1] + r1[2] + r1[3];
    partial[64 + blockIdx.x] = r2[0] + r2[1] + r2[2] + r2[3];
  }
}

// Pass 4: final 64->1 reduce, write scalar loss.
__global__ void pass4_final(const float* __restrict__ partial, float* __restrict__ out)
{
  int lane = threadIdx.x;
  float s = partial[lane] + partial[64 + lane];
  #pragma unroll
  for (int m = 1; m < 64; m <<= 1) s += __shfl_xor(s, m, 64);
  if (lane == 0) out[0] = s / (float)(B_ * N_);
}

extern "C" void kernel_launch(void* const* d_in, const int* in_sizes, int n_in,
                              void* d_out, int out_size, void* d_ws, size_t ws_size,
                              hipStream_t stream)
{
  const float* x = (const float*)d_in[0];
  const float* y = (const float*)d_in[1];
  char* ws = (char*)d_ws;

  unsigned short* xb = (unsigned short*)(ws);
  unsigned short* yb = (unsigned short*)(ws + (8u << 20));
  float*    x2     = (float*)   (ws + (16u << 20));
  float*    y2     = (float*)   (ws + (16u << 20) + (1u << 17));
  unsigned* rowmin = (unsigned*)(ws + (16u << 20) + (2u << 17));
  unsigned* colmin = (unsigned*)(ws + (16u << 20) + (3u << 17));
  float*    partial= (float*)   (ws + (16u << 20) + (4u << 17));
  float* outf = (float*)d_out;

  pass1_prep<<<(2 * B_ * N_) / 4, 256, 0, stream>>>(x, y, xb, yb, x2, y2, rowmin, colmin);

  pass2_tile<<<(N_ / 128) * CHUNKS * B_, 256, 0, stream>>>(xb, yb, x2, y2, rowmin, colmin);

  pass3_partial<<<64, 256, 0, stream>>>(rowmin, colmin, partial);
  pass4_final<<<1, 64, 0, stream>>>(partial, outf);
}